// Round 14
// baseline (237.719 us; speedup 1.0000x reference)
//
#include <hip/hip_runtime.h>
#include <hip/hip_bf16.h>
#include <math.h>

// SparseMLP: W=8 experts, per w: out = gelu(X @ W1 + b1) @ W2 + b2
// Round 14: 2-blocks/CU GEMM. BM=128, BN=256, BK=32, 512 thr (8 waves 2Mx4N,
// wave tile 64x64), LDS 48KB = 2 x (A 8KB + B 16KB) double buffer ->
// 2 blocks/CU (launch_bounds(512,4), VGPR<=128). Sync = R12 minimum: ONE
// barrier + ONE vmcnt(0) per K-tile, stage 1 tile ahead into nxt only (zero
// intra-tile WAR); co-resident block hides barrier/drain stalls (m114).
// 64-B rows: XOR swizzle byte ^= ((row>>1)&3)<<4 (2-way = free); staging
// source inverse-swizzled (rule #21): colblock (tid&3)^((tid>>3)&3).
// Frag ping-pong prefetch kept. Prep = R13 verbatim (single fused dispatch).

typedef float f32x4 __attribute__((ext_vector_type(4)));
typedef short bf16x8 __attribute__((ext_vector_type(8)));
typedef short bf16x4 __attribute__((ext_vector_type(4)));
typedef unsigned short u16;

#define NW 8
#define MDIM 2048   // BHS*SEQ
#define HDIM 2048
#define FFN  1024

static __device__ __forceinline__ u16 f32_to_bf16_rn(float f) {
  union { float f; unsigned u; } v; v.f = f;
  unsigned r = v.u + 0x7FFF + ((v.u >> 16) & 1);
  return (u16)(r >> 16);
}

static __device__ __forceinline__ void gload_lds16(const void* g, void* l) {
  __builtin_amdgcn_global_load_lds(
      (const __attribute__((address_space(1))) void*)g,
      (__attribute__((address_space(3))) void*)l, 16, 0, 0);
}

// ---------------- fused prep (R13 verbatim) ----------------
static __device__ __forceinline__ void transpose_body(
    const float* __restrict__ in, u16* __restrict__ out, int R, int C,
    int bx, int by, int bz, u16 (*tile)[68]) {
  int w = bz;
  int c0 = bx * 64, r0 = by * 64;
  int t = threadIdx.x;  // 256 threads
  const float* ip = in + (size_t)w * R * C;
  u16* op = out + (size_t)w * C * R;
  int tr = t >> 4;       // 0..15
  int tc4 = (t & 15) * 4;
#pragma unroll
  for (int j = 0; j < 4; ++j) {
    int r = tr + j * 16;
    f32x4 v = *(const f32x4*)(ip + (size_t)(r0 + r) * C + c0 + tc4);
    tile[r][tc4 + 0] = f32_to_bf16_rn(v.x);
    tile[r][tc4 + 1] = f32_to_bf16_rn(v.y);
    tile[r][tc4 + 2] = f32_to_bf16_rn(v.z);
    tile[r][tc4 + 3] = f32_to_bf16_rn(v.w);
  }
  __syncthreads();
#pragma unroll
  for (int j = 0; j < 4; ++j) {
    int c = tr + j * 16;
    bf16x4 p;
    p[0] = (short)tile[tc4 + 0][c];
    p[1] = (short)tile[tc4 + 1][c];
    p[2] = (short)tile[tc4 + 2][c];
    p[3] = (short)tile[tc4 + 3][c];
    *(bf16x4*)(op + (size_t)(c0 + c) * R + r0 + tc4) = p;
  }
}

#define NB_T1 4096
#define NB_T2 4096
#define NB_CV 32768

__global__ void prep_kernel(const float* __restrict__ hs,
                            const float* __restrict__ w1,
                            const float* __restrict__ w2,
                            const float* __restrict__ b2,
                            u16* __restrict__ Xb, u16* __restrict__ W1t,
                            u16* __restrict__ W2t, float* __restrict__ outb) {
  __shared__ u16 tile[64][68];
  int bid = blockIdx.x;
  if (bid < NB_T1) {
    transpose_body(w1, W1t, HDIM, FFN, bid % 16, (bid / 16) % 32, bid / 512,
                   tile);
    return;
  }
  bid -= NB_T1;
  if (bid < NB_T2) {
    transpose_body(w2, W2t, FFN, HDIM, bid % 32, (bid / 32) % 16, bid / 512,
                   tile);
    return;
  }
  bid -= NB_T2;
  if (bid < NB_CV) {
    size_t i = (size_t)bid * blockDim.x + threadIdx.x;
    f32x4 v = ((const f32x4*)hs)[i];
    bf16x4 p;
    p[0] = (short)f32_to_bf16_rn(v.x);
    p[1] = (short)f32_to_bf16_rn(v.y);
    p[2] = (short)f32_to_bf16_rn(v.z);
    p[3] = (short)f32_to_bf16_rn(v.w);
    ((bf16x4*)Xb)[i] = p;
    return;
  }
  bid -= NB_CV;
  {
    int i = bid * 256 + threadIdx.x;
    if (i < NW * HDIM) outb[i] = b2[i];
  }
}

// ---------------- GEMM ----------------
// Buffer (24KB): A [128 rows][64B] @0, B [256 rows][64B] @8192.
// Stage one K-tile: A = 1 sweep (512 thr x 16B = 8KB), B = 2 sweeps.
#define STAGE_T(dst, tt)                                                      \
  do {                                                                        \
    gload_lds16(gA + (size_t)(tt) * 64, (dst) + tid * 16);                    \
    gload_lds16(gB + (size_t)(tt) * 64, (dst) + 8192 + tid * 16);             \
    gload_lds16(gB + (size_t)128 * rowK + (size_t)(tt) * 64,                  \
                (dst) + 16384 + tid * 16);                                    \
  } while (0)

// A-frag pair h (i = 2h, 2h+1); B-frags all 4
#define LOAD_A(DST, SB, h)                                                    \
  _Pragma("unroll") for (int ii = 0; ii < 2; ++ii)                            \
      DST[ii] = *(const bf16x8*)((SB) +                                       \
          (wr * 64 + ((h)*2 + ii) * 16 + ra) * 64 + colsw)
#define LOAD_B(DST, SB)                                                       \
  _Pragma("unroll") for (int jj = 0; jj < 4; ++jj)                            \
      DST[jj] = *(const bf16x8*)((SB) + 8192 +                                \
          (wc * 64 + jj * 16 + ra) * 64 + colsw)

// 8-MFMA cluster for A-row-pair h using frags AF (B in bfr)
#define MFMA_H(h, AF)                                                         \
  {                                                                           \
    __builtin_amdgcn_s_setprio(1);                                            \
    _Pragma("unroll") for (int ii = 0; ii < 2; ++ii)                          \
        _Pragma("unroll") for (int jj = 0; jj < 4; ++jj)                      \
            acc[(h)*2 + ii][jj] =                                             \
                __builtin_amdgcn_mfma_f32_16x16x32_bf16(                      \
                    AF[ii], bfr[jj], acc[(h)*2 + ii][jj], 0, 0, 0);           \
    __builtin_amdgcn_s_setprio(0);                                            \
  }

template <bool GELU, bool C_F32>
__global__ __launch_bounds__(512, 4) void mlp_gemm(
    const u16* __restrict__ A, const u16* __restrict__ Bt,
    const float* __restrict__ bias, void* __restrict__ Cptr,
    int M, int N, int K, int nN) {
  __shared__ __align__(16) char lds[49152];
  char* cur = lds;
  char* nxt = lds + 24576;

  const int bid = blockIdx.x;
  const int w = bid & 7;            // expert -> pinned to XCD bid%8
  const int jb = bid >> 3;
  const int m0 = (jb / nN) * 128;
  const int n0 = (jb % nN) * 256;

  const int tid = threadIdx.x;
  const int wid = tid >> 6, lane = tid & 63;
  const int wr = wid >> 2, wc = wid & 3;   // 2 M-waves x 4 N-waves
  const int qa = lane >> 4, ra = lane & 15;

  const u16* ap = A + (size_t)w * M * K;
  const u16* btp = Bt + (size_t)w * N * K;
  const float* bp = bias + (size_t)w * N;

  const size_t rowK = (size_t)K * 2;       // bytes per K-row
  // staging source (inverse-swizzled): thread t -> row t>>2, colblock
  // (t&3) ^ ((t>>3)&3)  [row>>1 & 3 == (t>>3)&3]
  const int csw = (((tid & 3) ^ ((tid >> 3) & 3)) * 16);
  const char* gA = (const char*)ap + (size_t)(m0 + (tid >> 2)) * rowK + csw;
  const char* gB = (const char*)btp + (size_t)(n0 + (tid >> 2)) * rowK + csw;

  // fragment-read swizzled byte offset within a 64-B row
  const int colsw = (qa * 16) ^ ((((ra >> 1) & 3)) << 4);

  f32x4 acc[4][4];
#pragma unroll
  for (int i = 0; i < 4; ++i)
#pragma unroll
    for (int j = 0; j < 4; ++j)
#pragma unroll
      for (int r = 0; r < 4; ++r) acc[i][j][r] = 0.0f;

  const int NT = K >> 5;   // 32-wide K-tiles (GEMM1: 64, GEMM2: 32)

  // prologue: stage tile 0 -> cur; wait; preload B-frags + A pair 0
  STAGE_T(cur, 0);
  asm volatile("s_waitcnt vmcnt(0)" ::: "memory");
  __builtin_amdgcn_s_barrier();
  __builtin_amdgcn_sched_barrier(0);

  bf16x8 bfr[4], afrA[2], afrB[2];
  LOAD_B(bfr, cur);
  LOAD_A(afrA, cur, 0);

  for (int t = 0; t < NT; ++t) {
    const bool pf = (t + 1) < NT;
    if (pf) STAGE_T(nxt, t + 1);        // 3 gloads, issued before compute
    __builtin_amdgcn_sched_barrier(0);  // pin stage-issue before compute

    LOAD_A(afrB, cur, 1);
    MFMA_H(0, afrA);
    MFMA_H(1, afrB);

    asm volatile("s_waitcnt vmcnt(0)" ::: "memory");  // t+1's loads landed
    __builtin_amdgcn_s_barrier();
    __builtin_amdgcn_sched_barrier(0);  // nothing hoists above the barrier

    if (pf) {
      LOAD_B(bfr, nxt);
      LOAD_A(afrA, nxt, 0);
    }
    char* tp = cur; cur = nxt; nxt = tp;
  }

  // epilogue: + bias, optional exact GELU, store
#pragma unroll
  for (int i = 0; i < 4; ++i) {
#pragma unroll
    for (int j = 0; j < 4; ++j) {
      int col = n0 + wc * 64 + j * 16 + ra;
      float bv = bp[col];
#pragma unroll
      for (int r = 0; r < 4; ++r) {
        int row = m0 + wr * 64 + i * 16 + qa * 4 + r;
        float v = acc[i][j][r] + bv;
        if (GELU) v = 0.5f * v * (1.0f + erff(v * 0.70710678118654752f));
        if (C_F32)
          ((float*)Cptr)[(size_t)w * M * N + (size_t)row * N + col] = v;
        else
          ((u16*)Cptr)[(size_t)w * M * N + (size_t)row * N + col] =
              f32_to_bf16_rn(v);
      }
    }
  }
}

extern "C" void kernel_launch(void* const* d_in, const int* in_sizes, int n_in,
                              void* d_out, int out_size, void* d_ws,
                              size_t ws_size, hipStream_t stream) {
  const float* hs = (const float*)d_in[0];  // (8,2,1024,2048) f32
  const float* w1 = (const float*)d_in[1];  // (8,2048,1024) f32
  const float* b1 = (const float*)d_in[2];  // (8,1,1024) f32
  const float* w2 = (const float*)d_in[3];  // (8,1024,2048) f32
  const float* b2 = (const float*)d_in[4];  // (8,2048) f32

  // ws (u16): W1t (8,1024,2048) | W2t (8,2048,1024) | inter (8,2048,1024) | Xb
  u16* W1t = (u16*)d_ws;
  u16* W2t = W1t + (size_t)NW * FFN * HDIM;
  u16* inter = W2t + (size_t)NW * HDIM * FFN;
  u16* XbWs = inter + (size_t)NW * MDIM * FFN;
  size_t need = ((size_t)NW * FFN * HDIM * 2 + (size_t)NW * MDIM * FFN +
                 (size_t)NW * MDIM * HDIM) * sizeof(u16);
  u16* Xb = (ws_size >= need) ? XbWs : (u16*)d_out;

  float* outb = (float*)d_out + (size_t)NW * MDIM * HDIM;

  // single fused prep dispatch: w1^T | w2^T | X->bf16 | bias tail
  prep_kernel<<<dim3(NB_T1 + NB_T2 + NB_CV + 16), 256, 0, stream>>>(
      hs, w1, w2, b2, Xb, W1t, W2t, outb);

  // inter = gelu(X @ W1 + b1)  [bf16]  M=2048 N=1024 K=2048 -> 512 blocks
  mlp_gemm<true, false>
      <<<dim3(NW * (MDIM / 128) * (FFN / 256)), 512, 0, stream>>>(
          Xb, W1t, b1, inter, MDIM, FFN, HDIM, FFN / 256);
  // out = inter @ W2 + b2  [f32]  M=2048 N=2048 K=1024 -> 1024 blocks
  mlp_gemm<false, true>
      <<<dim3(NW * (MDIM / 128) * (HDIM / 256)), 512, 0, stream>>>(
          inter, W2t, b2, d_out, MDIM, HDIM, FFN, HDIM / 256);
}

// Round 15
// 226.906 us; speedup vs baseline: 1.0477x; 1.0477x over previous
//
#include <hip/hip_runtime.h>
#include <hip/hip_bf16.h>
#include <math.h>

// SparseMLP: W=8 experts, per w: out = gelu(X @ W1 + b1) @ W2 + b2
// FINAL (= Round 13, session best 227.2 us): R12 GEMMs (256x256x64, 8 waves,
// 1 barrier + 1 vmcnt per K-tile, frag ping-pong prefetch, XOR-swizzled LDS
// via pre-swizzled gload source, expert->XCD pinning) + single fused prep
// dispatch (w1^T | w2^T | X->bf16 | bias tail, proven per-block bodies).
// R14's 2-blocks/CU quadrant measured net-negative (RF budget forces a
// smaller tile => 1.5x staged-bytes/FLOP); reverted per pre-commitment.

typedef float f32x4 __attribute__((ext_vector_type(4)));
typedef short bf16x8 __attribute__((ext_vector_type(8)));
typedef short bf16x4 __attribute__((ext_vector_type(4)));
typedef unsigned short u16;

#define NW 8
#define MDIM 2048   // BHS*SEQ
#define HDIM 2048
#define FFN  1024

static __device__ __forceinline__ u16 f32_to_bf16_rn(float f) {
  union { float f; unsigned u; } v; v.f = f;
  unsigned r = v.u + 0x7FFF + ((v.u >> 16) & 1);
  return (u16)(r >> 16);
}

static __device__ __forceinline__ void gload_lds16(const void* g, void* l) {
  __builtin_amdgcn_global_load_lds(
      (const __attribute__((address_space(1))) void*)g,
      (__attribute__((address_space(3))) void*)l, 16, 0, 0);
}

// ---------------- fused prep ----------------
static __device__ __forceinline__ void transpose_body(
    const float* __restrict__ in, u16* __restrict__ out, int R, int C,
    int bx, int by, int bz, u16 (*tile)[68]) {
  int w = bz;
  int c0 = bx * 64, r0 = by * 64;
  int t = threadIdx.x;  // 256 threads
  const float* ip = in + (size_t)w * R * C;
  u16* op = out + (size_t)w * C * R;
  int tr = t >> 4;       // 0..15
  int tc4 = (t & 15) * 4;
#pragma unroll
  for (int j = 0; j < 4; ++j) {
    int r = tr + j * 16;
    f32x4 v = *(const f32x4*)(ip + (size_t)(r0 + r) * C + c0 + tc4);
    tile[r][tc4 + 0] = f32_to_bf16_rn(v.x);
    tile[r][tc4 + 1] = f32_to_bf16_rn(v.y);
    tile[r][tc4 + 2] = f32_to_bf16_rn(v.z);
    tile[r][tc4 + 3] = f32_to_bf16_rn(v.w);
  }
  __syncthreads();
#pragma unroll
  for (int j = 0; j < 4; ++j) {
    int c = tr + j * 16;
    bf16x4 p;
    p[0] = (short)tile[tc4 + 0][c];
    p[1] = (short)tile[tc4 + 1][c];
    p[2] = (short)tile[tc4 + 2][c];
    p[3] = (short)tile[tc4 + 3][c];
    *(bf16x4*)(op + (size_t)(c0 + c) * R + r0 + tc4) = p;
  }
}

#define NB_T1 4096   // (FFN/64) x (HDIM/64) x NW
#define NB_T2 4096   // (HDIM/64) x (FFN/64) x NW
#define NB_CV 32768  // NW*MDIM*HDIM/4/256

__global__ void prep_kernel(const float* __restrict__ hs,
                            const float* __restrict__ w1,
                            const float* __restrict__ w2,
                            const float* __restrict__ b2,
                            u16* __restrict__ Xb, u16* __restrict__ W1t,
                            u16* __restrict__ W2t, float* __restrict__ outb) {
  __shared__ u16 tile[64][68];
  int bid = blockIdx.x;
  if (bid < NB_T1) {  // w1 (R=HDIM,C=FFN) -> W1t
    transpose_body(w1, W1t, HDIM, FFN, bid % 16, (bid / 16) % 32, bid / 512,
                   tile);
    return;
  }
  bid -= NB_T1;
  if (bid < NB_T2) {  // w2 (R=FFN,C=HDIM) -> W2t
    transpose_body(w2, W2t, FFN, HDIM, bid % 32, (bid / 32) % 16, bid / 512,
                   tile);
    return;
  }
  bid -= NB_T2;
  if (bid < NB_CV) {  // X -> bf16
    size_t i = (size_t)bid * blockDim.x + threadIdx.x;  // f32x4 index
    f32x4 v = ((const f32x4*)hs)[i];
    bf16x4 p;
    p[0] = (short)f32_to_bf16_rn(v.x);
    p[1] = (short)f32_to_bf16_rn(v.y);
    p[2] = (short)f32_to_bf16_rn(v.z);
    p[3] = (short)f32_to_bf16_rn(v.w);
    ((bf16x4*)Xb)[i] = p;
    return;
  }
  bid -= NB_CV;
  {  // bias tail
    int i = bid * 256 + threadIdx.x;
    if (i < NW * HDIM) outb[i] = b2[i];
  }
}

// ---------------- GEMM ----------------
// LDS layout per K-tile buffer (64KB): A0 @0, A1 @16384, B0 @32768, B1 @49152
#define STAGE_AH(dst, tt, h)                                                  \
  do {                                                                        \
    gload_lds16(gA + (size_t)(h) * 128 * rowK + (size_t)(tt) * 128,           \
                (dst) + (h) * 16384 + tid * 16);                              \
    gload_lds16(gA + ((size_t)(h) * 128 + 64) * rowK + (size_t)(tt) * 128,    \
                (dst) + (h) * 16384 + 8192 + tid * 16);                       \
  } while (0)
#define STAGE_BH(dst, tt, h)                                                  \
  do {                                                                        \
    gload_lds16(gB + (size_t)(h) * 128 * rowK + (size_t)(tt) * 128,           \
                (dst) + 32768 + (h) * 16384 + tid * 16);                      \
    gload_lds16(gB + ((size_t)(h) * 128 + 64) * rowK + (size_t)(tt) * 128,    \
                (dst) + 32768 + (h) * 16384 + 8192 + tid * 16);               \
  } while (0)

#define LOAD_A(DST, SB, q)                                                    \
  _Pragma("unroll") for (int ii = 0; ii < 2; ++ii)                            \
      _Pragma("unroll") for (int kk = 0; kk < 2; ++kk)                        \
          DST[ii][kk] = *(const bf16x8*)((SB) + Aoff +                        \
              ((q)*32 + ii * 16 + ra) * 128 + (colsw ^ (kk << 6)))
#define LOAD_B(DST, SB)                                                       \
  _Pragma("unroll") for (int jj = 0; jj < 4; ++jj)                            \
      _Pragma("unroll") for (int kk = 0; kk < 2; ++kk)                        \
          DST[jj][kk] = *(const bf16x8*)((SB) + Boff +                        \
              (brow + jj * 16 + ra) * 128 + (colsw ^ (kk << 6)))

#define MFMA_Q(q, AF)                                                         \
  {                                                                           \
    __builtin_amdgcn_s_setprio(1);                                            \
    _Pragma("unroll") for (int ii = 0; ii < 2; ++ii)                          \
        _Pragma("unroll") for (int jj = 0; jj < 4; ++jj)                      \
            _Pragma("unroll") for (int kk = 0; kk < 2; ++kk)                  \
                acc[(q)*2 + ii][jj] =                                         \
                    __builtin_amdgcn_mfma_f32_16x16x32_bf16(                  \
                        AF[ii][kk], bfr[jj][kk], acc[(q)*2 + ii][jj],         \
                        0, 0, 0);                                             \
    __builtin_amdgcn_s_setprio(0);                                            \
  }

template <bool GELU, bool C_F32>
__global__ __launch_bounds__(512, 2) void mlp_gemm(
    const u16* __restrict__ A, const u16* __restrict__ Bt,
    const float* __restrict__ bias, void* __restrict__ Cptr,
    int M, int N, int K, int nN) {
  __shared__ __align__(16) char lds[131072];
  char* cur = lds;
  char* nxt = lds + 65536;

  const int bid = blockIdx.x;
  const int w = bid & 7;            // expert -> pinned to XCD bid%8
  const int jb = bid >> 3;
  const int m0 = (jb / nN) * 256;
  const int n0 = (jb % nN) * 256;

  const int tid = threadIdx.x;
  const int wid = tid >> 6, lane = tid & 63;
  const int wr = wid >> 2, wc = wid & 3;   // 2 M-waves x 4 N-waves
  const int qa = lane >> 4, ra = lane & 15;

  const u16* ap = A + (size_t)w * M * K;
  const u16* btp = Bt + (size_t)w * N * K;
  const float* bp = bias + (size_t)w * N;

  const size_t rowK = (size_t)K * 2;
  const int r8 = tid >> 3;
  const int csw = ((tid & 7) * 16) ^ ((r8 & 7) << 4);
  const char* gA = (const char*)ap + (size_t)(m0 + r8) * rowK + csw;
  const char* gB = (const char*)btp + (size_t)(n0 + r8) * rowK + csw;

  const int colsw = (qa * 16) ^ ((ra & 7) << 4);
  const int Aoff = wr * 16384;
  const int Boff = 32768 + (wc >> 1) * 16384;
  const int brow = (wc & 1) * 64;

  f32x4 acc[8][4];
#pragma unroll
  for (int i = 0; i < 8; ++i)
#pragma unroll
    for (int j = 0; j < 4; ++j)
#pragma unroll
      for (int r = 0; r < 4; ++r) acc[i][j][r] = 0.0f;

  const int NT = K >> 6;

  // prologue: stage tile 0 -> cur; wait; preload its B-frags + A-q0 frags
  STAGE_AH(cur, 0, 0); STAGE_AH(cur, 0, 1);
  STAGE_BH(cur, 0, 0); STAGE_BH(cur, 0, 1);
  asm volatile("s_waitcnt vmcnt(0)" ::: "memory");
  __builtin_amdgcn_s_barrier();
  __builtin_amdgcn_sched_barrier(0);

  bf16x8 bfr[4][2], afrA[2][2], afrB[2][2];
  LOAD_B(bfr, cur);
  LOAD_A(afrA, cur, 0);

  for (int t = 0; t < NT; ++t) {
    const bool pf = (t + 1) < NT;
    if (pf) {
      STAGE_AH(nxt, t + 1, 0); STAGE_AH(nxt, t + 1, 1);
      STAGE_BH(nxt, t + 1, 0); STAGE_BH(nxt, t + 1, 1);
    }
    __builtin_amdgcn_sched_barrier(0);   // pin stage-issue before compute

    LOAD_A(afrB, cur, 1);
    MFMA_Q(0, afrA);
    LOAD_A(afrA, cur, 2);
    MFMA_Q(1, afrB);
    LOAD_A(afrB, cur, 3);
    MFMA_Q(2, afrA);
    MFMA_Q(3, afrB);

    asm volatile("s_waitcnt vmcnt(0)" ::: "memory");  // t+1's 8 loads landed
    __builtin_amdgcn_s_barrier();
    __builtin_amdgcn_sched_barrier(0);   // nothing hoists above the barrier

    if (pf) {
      LOAD_B(bfr, nxt);
      LOAD_A(afrA, nxt, 0);
    }
    char* tp = cur; cur = nxt; nxt = tp;
  }

  // epilogue: + bias, optional exact GELU, store
#pragma unroll
  for (int i = 0; i < 8; ++i) {
#pragma unroll
    for (int j = 0; j < 4; ++j) {
      int col = n0 + wc * 64 + j * 16 + ra;
      float bv = bp[col];
#pragma unroll
      for (int r = 0; r < 4; ++r) {
        int row = m0 + wr * 128 + i * 16 + qa * 4 + r;
        float v = acc[i][j][r] + bv;
        if (GELU) v = 0.5f * v * (1.0f + erff(v * 0.70710678118654752f));
        if (C_F32)
          ((float*)Cptr)[(size_t)w * M * N + (size_t)row * N + col] = v;
        else
          ((u16*)Cptr)[(size_t)w * M * N + (size_t)row * N + col] =
              f32_to_bf16_rn(v);
      }
    }
  }
}

extern "C" void kernel_launch(void* const* d_in, const int* in_sizes, int n_in,
                              void* d_out, int out_size, void* d_ws,
                              size_t ws_size, hipStream_t stream) {
  const float* hs = (const float*)d_in[0];  // (8,2,1024,2048) f32
  const float* w1 = (const float*)d_in[1];  // (8,2048,1024) f32
  const float* b1 = (const float*)d_in[2];  // (8,1,1024) f32
  const float* w2 = (const float*)d_in[3];  // (8,1024,2048) f32
  const float* b2 = (const float*)d_in[4];  // (8,2048) f32

  // ws (u16): W1t (8,1024,2048) | W2t (8,2048,1024) | inter (8,2048,1024) | Xb
  u16* W1t = (u16*)d_ws;
  u16* W2t = W1t + (size_t)NW * FFN * HDIM;
  u16* inter = W2t + (size_t)NW * HDIM * FFN;
  u16* XbWs = inter + (size_t)NW * MDIM * FFN;
  size_t need = ((size_t)NW * FFN * HDIM * 2 + (size_t)NW * MDIM * FFN +
                 (size_t)NW * MDIM * HDIM) * sizeof(u16);
  u16* Xb = (ws_size >= need) ? XbWs : (u16*)d_out;

  float* outb = (float*)d_out + (size_t)NW * MDIM * HDIM;

  // single fused prep dispatch: w1^T | w2^T | X->bf16 | bias tail
  prep_kernel<<<dim3(NB_T1 + NB_T2 + NB_CV + 16), 256, 0, stream>>>(
      hs, w1, w2, b2, Xb, W1t, W2t, outb);

  // inter = gelu(X @ W1 + b1)  [bf16]  M=2048 N=1024 K=2048 -> 256 blocks
  mlp_gemm<true, false>
      <<<dim3(NW * (MDIM / 256) * (FFN / 256)), 512, 0, stream>>>(
          Xb, W1t, b1, inter, MDIM, FFN, HDIM, FFN / 256);
  // out = inter @ W2 + b2  [f32]  M=2048 N=2048 K=1024 -> 512 blocks
  mlp_gemm<false, true>
      <<<dim3(NW * (MDIM / 256) * (HDIM / 256)), 512, 0, stream>>>(
          inter, W2t, b2, d_out, MDIM, HDIM, FFN, HDIM / 256);
}